// Round 2
// baseline (228404.810 us; speedup 1.0000x reference)
//
#include <hip/hip_runtime.h>
#include <stddef.h>
#include <stdint.h>

#define BB 256   // batch
#define TT 512   // time steps
#define DD 128   // input/output dim
#define HH 256   // hidden size

#define NGROUP 8            // batch groups (32 batch each)
#define WG_PER_GROUP 64     // workgroups per batch group
#define NWG (NGROUP * WG_PER_GROUP)   // 512 workgroups total

__device__ __forceinline__ float sigm(float x)  { return 1.0f / (1.0f + __expf(-x)); }
__device__ __forceinline__ float tanh_(float x) { return 2.0f / (1.0f + __expf(-2.0f * x)) - 1.0f; }

// ---------------- group barrier (64 WGs, device-scope) ----------------
__device__ __forceinline__ void group_barrier(unsigned int* cnt, unsigned int* gen)
{
    __syncthreads();   // all waves of this WG arrived; their stores are drained (vmcnt0 at barrier)
    if (threadIdx.x == 0) {
        __threadfence();   // release: make this WG's h-writes visible device-wide
        unsigned int g   = __hip_atomic_load(gen, __ATOMIC_RELAXED, __HIP_MEMORY_SCOPE_AGENT);
        unsigned int old = __hip_atomic_fetch_add(cnt, 1u, __ATOMIC_ACQ_REL, __HIP_MEMORY_SCOPE_AGENT);
        if (old == (unsigned int)(WG_PER_GROUP - 1)) {
            __hip_atomic_store(cnt, 0u, __ATOMIC_RELAXED, __HIP_MEMORY_SCOPE_AGENT);
            __hip_atomic_fetch_add(gen, 1u, __ATOMIC_RELEASE, __HIP_MEMORY_SCOPE_AGENT);
        } else {
            while (__hip_atomic_load(gen, __ATOMIC_ACQUIRE, __HIP_MEMORY_SCOPE_AGENT) == g)
                __builtin_amdgcn_s_sleep(2);
        }
    }
    __syncthreads();
    __threadfence();   // acquire: don't serve stale h from local caches
}

// ---------------- dot helpers ----------------
// hb is pre-offset by global batch index; stride 256 floats per k. Weight rows are
// wave-uniform (bases derived from readfirstlane'd unit) -> scalar s_loads.
__device__ __forceinline__ void dot4(const float* __restrict__ w0, const float* __restrict__ w1,
                                     const float* __restrict__ w2, const float* __restrict__ w3,
                                     const float* __restrict__ hb, int k0, int k1,
                                     float& a0, float& a1, float& a2, float& a3)
{
    #pragma unroll 8
    for (int k = k0; k < k1; ++k) {
        const float hv = hb[k * 256];
        a0 = fmaf(w0[k], hv, a0);
        a1 = fmaf(w1[k], hv, a1);
        a2 = fmaf(w2[k], hv, a2);
        a3 = fmaf(w3[k], hv, a3);
    }
}

// x part: per-lane contiguous row (L1-cached)
__device__ __forceinline__ void dotx(const float* __restrict__ w0, const float* __restrict__ w1,
                                     const float* __restrict__ w2, const float* __restrict__ w3,
                                     const float* __restrict__ xp, int n,
                                     float& a0, float& a1, float& a2, float& a3)
{
    #pragma unroll 8
    for (int k = 0; k < n; ++k) {
        const float xv = xp[k];
        a0 = fmaf(w0[k], xv, a0);
        a1 = fmaf(w1[k], xv, a1);
        a2 = fmaf(w2[k], xv, a2);
        a3 = fmaf(w3[k], xv, a3);
    }
}

// ---------------- persistent kernel ----------------
__global__ __launch_bounds__(256, 2) void lstm_ae_persistent(
    const float* __restrict__ x,
    const float* __restrict__ eWih0, const float* __restrict__ eWhh0,
    const float* __restrict__ ebih0, const float* __restrict__ ebhh0,
    const float* __restrict__ eWih1, const float* __restrict__ eWhh1,
    const float* __restrict__ ebih1, const float* __restrict__ ebhh1,
    const float* __restrict__ dWhh0, const float* __restrict__ dbih0, const float* __restrict__ dbhh0,
    const float* __restrict__ dWih1, const float* __restrict__ dWhh1,
    const float* __restrict__ dbih1, const float* __restrict__ dbhh1,
    const float* __restrict__ Mm,   const float* __restrict__ bM,
    const float* __restrict__ fcW,  const float* __restrict__ fcb,
    float* __restrict__ h1a, float* __restrict__ h1b,
    float* __restrict__ h2a, float* __restrict__ h2b,
    unsigned int* __restrict__ bar,
    float* __restrict__ out)
{
    const int wg = blockIdx.x;
    const int g  = wg & 7;                 // batch group
    const int m  = wg >> 3;                // 0..63 within group
    const int w  = __builtin_amdgcn_readfirstlane((int)(threadIdx.x >> 6));  // wave 0..3
    const int lane = (int)(threadIdx.x & 63);
    const int kh = lane >> 5;              // K-half
    const int b  = lane & 31;              // batch within group
    const int u  = __builtin_amdgcn_readfirstlane(m * 4 + w);   // hidden unit 0..255
    const int bg = g * 32 + b;             // global batch index

    unsigned int* cnt = bar + g * 16;        // 64B-separated per group
    unsigned int* gen = bar + 128 + g * 16;

    // gate row indices (PyTorch order i,f,g,o)
    const int r0 = u, r1 = HH + u, r2 = 2*HH + u, r3 = 3*HH + u;

    // wave-uniform weight row pointers
    const float* exw0 = eWih0 + (size_t)r0 * DD;
    const float* exw1 = eWih0 + (size_t)r1 * DD;
    const float* exw2 = eWih0 + (size_t)r2 * DD;
    const float* exw3 = eWih0 + (size_t)r3 * DD;
    const float* ehw0 = eWhh0 + (size_t)r0 * HH;
    const float* ehw1 = eWhh0 + (size_t)r1 * HH;
    const float* ehw2 = eWhh0 + (size_t)r2 * HH;
    const float* ehw3 = eWhh0 + (size_t)r3 * HH;
    const float* e1x0 = eWih1 + (size_t)r0 * HH;
    const float* e1x1 = eWih1 + (size_t)r1 * HH;
    const float* e1x2 = eWih1 + (size_t)r2 * HH;
    const float* e1x3 = eWih1 + (size_t)r3 * HH;
    const float* e1h0 = eWhh1 + (size_t)r0 * HH;
    const float* e1h1 = eWhh1 + (size_t)r1 * HH;
    const float* e1h2 = eWhh1 + (size_t)r2 * HH;
    const float* e1h3 = eWhh1 + (size_t)r3 * HH;
    const float* M0   = Mm    + (size_t)r0 * HH;
    const float* M1   = Mm    + (size_t)r1 * HH;
    const float* M2   = Mm    + (size_t)r2 * HH;
    const float* M3   = Mm    + (size_t)r3 * HH;
    const float* d0h0 = dWhh0 + (size_t)r0 * HH;
    const float* d0h1 = dWhh0 + (size_t)r1 * HH;
    const float* d0h2 = dWhh0 + (size_t)r2 * HH;
    const float* d0h3 = dWhh0 + (size_t)r3 * HH;
    const float* d1x0 = dWih1 + (size_t)r0 * HH;
    const float* d1x1 = dWih1 + (size_t)r1 * HH;
    const float* d1x2 = dWih1 + (size_t)r2 * HH;
    const float* d1x3 = dWih1 + (size_t)r3 * HH;
    const float* d1h0 = dWhh1 + (size_t)r0 * HH;
    const float* d1h1 = dWhh1 + (size_t)r1 * HH;
    const float* d1h2 = dWhh1 + (size_t)r2 * HH;
    const float* d1h3 = dWhh1 + (size_t)r3 * HH;

    // bias sums (uniform scalar loads)
    const float eb0_0 = ebih0[r0] + ebhh0[r0];
    const float eb0_1 = ebih0[r1] + ebhh0[r1];
    const float eb0_2 = ebih0[r2] + ebhh0[r2];
    const float eb0_3 = ebih0[r3] + ebhh0[r3];
    const float eb1_0 = ebih1[r0] + ebhh1[r0];
    const float eb1_1 = ebih1[r1] + ebhh1[r1];
    const float eb1_2 = ebih1[r2] + ebhh1[r2];
    const float eb1_3 = ebih1[r3] + ebhh1[r3];
    const float db0_0 = dbih0[r0] + dbhh0[r0];
    const float db0_1 = dbih0[r1] + dbhh0[r1];
    const float db0_2 = dbih0[r2] + dbhh0[r2];
    const float db0_3 = dbih0[r3] + dbhh0[r3];
    const float db1_0 = dbih1[r0] + dbhh1[r0];
    const float db1_1 = dbih1[r1] + dbhh1[r1];
    const float db1_2 = dbih1[r2] + dbhh1[r2];
    const float db1_3 = dbih1[r3] + dbhh1[r3];
    const float bM0 = bM[r0], bM1 = bM[r1], bM2 = bM[r2], bM3 = bM[r3];

    float c1 = 0.f, c2 = 0.f;
    float* h1buf[2] = { h1a, h1b };
    float* h2buf[2] = { h2a, h2b };
    const int hidx = u * 256 + bg;   // store index for this (u, b)

    // ---------------- encoder ----------------
    for (int t = 0; t < TT; ++t) {
        const int p = t & 1;
        const float* h1p = h1buf[p] + bg;
        const float* h2p = h2buf[p] + bg;
        float* h1n = h1buf[p ^ 1];
        float* h2n = h2buf[p ^ 1];

        // ---- layer 0: gates = Wih0 @ x(t) + Whh0 @ h1p + b ----
        float a0 = 0.f, a1 = 0.f, a2 = 0.f, a3 = 0.f;
        if (kh == 0) {
            const float* xp = x + (size_t)bg * (TT * DD) + (size_t)t * DD;
            dotx(exw0, exw1, exw2, exw3, xp, DD, a0, a1, a2, a3);
            dot4(ehw0, ehw1, ehw2, ehw3, h1p, 0, 64, a0, a1, a2, a3);
        } else {
            dot4(ehw0, ehw1, ehw2, ehw3, h1p, 64, 256, a0, a1, a2, a3);
        }
        a0 += __shfl_xor(a0, 32); a1 += __shfl_xor(a1, 32);
        a2 += __shfl_xor(a2, 32); a3 += __shfl_xor(a3, 32);
        a0 += eb0_0; a1 += eb0_1; a2 += eb0_2; a3 += eb0_3;
        c1 = sigm(a1) * c1 + sigm(a0) * tanh_(a2);
        {
            float hv = sigm(a3) * tanh_(c1);
            if (lane < 32) h1n[hidx] = hv;
        }
        group_barrier(cnt, gen);

        // ---- layer 1: gates = Wih1 @ h1n + Whh1 @ h2p + b ----
        a0 = 0.f; a1 = 0.f; a2 = 0.f; a3 = 0.f;
        if (kh == 0) dot4(e1x0, e1x1, e1x2, e1x3, h1n + bg, 0, 256, a0, a1, a2, a3);
        else         dot4(e1h0, e1h1, e1h2, e1h3, h2p,      0, 256, a0, a1, a2, a3);
        a0 += __shfl_xor(a0, 32); a1 += __shfl_xor(a1, 32);
        a2 += __shfl_xor(a2, 32); a3 += __shfl_xor(a3, 32);
        a0 += eb1_0; a1 += eb1_1; a2 += eb1_2; a3 += eb1_3;
        c2 = sigm(a1) * c2 + sigm(a0) * tanh_(a2);
        {
            float hv = sigm(a3) * tanh_(c2);
            if (lane < 32) h2n[hidx] = hv;
        }
        group_barrier(cnt, gen);
    }

    // ---------------- decoder (fc folded into d0 via M) ----------------
    for (int s = 0; s < TT; ++s) {
        const int p = s & 1;
        const float* h1p = h1buf[p] + bg;
        const float* h2p = h2buf[p] + bg;
        float* h1n = h1buf[p ^ 1];
        float* h2n = h2buf[p ^ 1];

        // ---- d0': gates = M @ h2p (==Wih_d0 @ y(s-1)) + Whh_d0 @ h1p + b (+bM) ----
        float a0 = 0.f, a1 = 0.f, a2 = 0.f, a3 = 0.f;
        if (kh == 0) {
            if (s > 0) dot4(M0, M1, M2, M3, h2p, 0, 256, a0, a1, a2, a3);
        } else {
            dot4(d0h0, d0h1, d0h2, d0h3, h1p, 0, 256, a0, a1, a2, a3);
        }
        a0 += __shfl_xor(a0, 32); a1 += __shfl_xor(a1, 32);
        a2 += __shfl_xor(a2, 32); a3 += __shfl_xor(a3, 32);
        a0 += db0_0; a1 += db0_1; a2 += db0_2; a3 += db0_3;
        if (s > 0) { a0 += bM0; a1 += bM1; a2 += bM2; a3 += bM3; }
        c1 = sigm(a1) * c1 + sigm(a0) * tanh_(a2);
        {
            float hv = sigm(a3) * tanh_(c1);
            if (lane < 32) h1n[hidx] = hv;
        }
        group_barrier(cnt, gen);

        // ---- d1: gates = Wih_d1 @ h1n + Whh_d1 @ h2p + b ----
        a0 = 0.f; a1 = 0.f; a2 = 0.f; a3 = 0.f;
        if (kh == 0) dot4(d1x0, d1x1, d1x2, d1x3, h1n + bg, 0, 256, a0, a1, a2, a3);
        else         dot4(d1h0, d1h1, d1h2, d1h3, h2p,      0, 256, a0, a1, a2, a3);
        a0 += __shfl_xor(a0, 32); a1 += __shfl_xor(a1, 32);
        a2 += __shfl_xor(a2, 32); a3 += __shfl_xor(a3, 32);
        a0 += db1_0; a1 += db1_1; a2 += db1_2; a3 += db1_3;
        c2 = sigm(a1) * c2 + sigm(a0) * tanh_(a2);
        {
            float hv = sigm(a3) * tanh_(c2);
            if (lane < 32) h2n[hidx] = hv;
        }
        group_barrier(cnt, gen);

        // ---- fc output: y(s) = fc_W @ h2n + fc_b  (pure output, off critical path) ----
        if (w < 2) {
            const int d = __builtin_amdgcn_readfirstlane(2 * m + w);
            const float* fr = fcW + (size_t)d * HH;
            const float* hq = h2n + bg;
            float acc = 0.f;
            const int k0 = kh * 128, k1 = k0 + 128;
            #pragma unroll 8
            for (int k = k0; k < k1; ++k)
                acc = fmaf(fr[k], hq[k * 256], acc);
            acc += __shfl_xor(acc, 32);
            acc += fcb[d];
            if (kh == 0)
                out[(size_t)bg * (TT * DD) + (size_t)s * DD + d] = acc;
        }
    }
}

// ---------------- prep kernels ----------------
// M[r][j] = sum_d Wih_d0[r][d] * fc_W[d][j]   (r<1024, j<256, d<128)
__global__ __launch_bounds__(256) void prep_M(const float* __restrict__ Wih_d0,
                                              const float* __restrict__ fcW,
                                              float* __restrict__ Mm)
{
    const int r = blockIdx.x;
    const int j = threadIdx.x;
    float acc = 0.f;
    #pragma unroll 8
    for (int d = 0; d < DD; ++d)
        acc = fmaf(Wih_d0[(size_t)r * DD + d], fcW[(size_t)d * HH + j], acc);
    Mm[(size_t)r * HH + j] = acc;
}

// bM[r] = sum_d Wih_d0[r][d] * fc_b[d]
__global__ __launch_bounds__(256) void prep_bM(const float* __restrict__ Wih_d0,
                                               const float* __restrict__ fcb,
                                               float* __restrict__ bM)
{
    const int r = blockIdx.x * 256 + threadIdx.x;
    if (r < 4 * HH) {
        float acc = 0.f;
        #pragma unroll 8
        for (int d = 0; d < DD; ++d)
            acc = fmaf(Wih_d0[(size_t)r * DD + d], fcb[d], acc);
        bM[r] = acc;
    }
}

__global__ __launch_bounds__(256) void zero_kernel(float* __restrict__ p, int n)
{
    int i = blockIdx.x * 256 + threadIdx.x;
    if (i < n) p[i] = 0.0f;
}

// ---------------- launch ----------------
extern "C" void kernel_launch(void* const* d_in, const int* in_sizes, int n_in,
                              void* d_out, int out_size, void* d_ws, size_t ws_size,
                              hipStream_t stream)
{
    const float* x       = (const float*)d_in[0];
    const float* e_Wih0  = (const float*)d_in[1];
    const float* e_Whh0  = (const float*)d_in[2];
    const float* e_bih0  = (const float*)d_in[3];
    const float* e_bhh0  = (const float*)d_in[4];
    const float* e_Wih1  = (const float*)d_in[5];
    const float* e_Whh1  = (const float*)d_in[6];
    const float* e_bih1  = (const float*)d_in[7];
    const float* e_bhh1  = (const float*)d_in[8];
    const float* d_Wih0  = (const float*)d_in[9];
    const float* d_Whh0  = (const float*)d_in[10];
    const float* d_bih0  = (const float*)d_in[11];
    const float* d_bhh0  = (const float*)d_in[12];
    const float* d_Wih1  = (const float*)d_in[13];
    const float* d_Whh1  = (const float*)d_in[14];
    const float* d_bih1  = (const float*)d_in[15];
    const float* d_bhh1  = (const float*)d_in[16];
    const float* fc_W    = (const float*)d_in[17];
    const float* fc_b    = (const float*)d_in[18];
    float* out = (float*)d_out;

    // ws layout (floats):
    //   [0,1024)        barrier area (uints)
    //   [1024,  +65536) h1_0   [66560, +65536) h1_1
    //   [132096,+65536) h2_0   [197632,+65536) h2_1
    //   [263168,+262144) M     [525312,+1024) bM
    float* ws = (float*)d_ws;
    unsigned int* bar = (unsigned int*)ws;
    float* h1a = ws + 1024;
    float* h1b = ws + 66560;
    float* h2a = ws + 132096;
    float* h2b = ws + 197632;
    float* Mm  = ws + 263168;
    float* bM  = ws + 525312;
    const int zero_n = 263168;   // barriers + h buffers

    zero_kernel<<<(zero_n + 255) / 256, 256, 0, stream>>>(ws, zero_n);
    prep_M<<<4 * HH, 256, 0, stream>>>(d_Wih0, fc_W, Mm);
    prep_bM<<<4, 256, 0, stream>>>(d_Wih0, fc_b, bM);

    void* args[] = {
        (void*)&x,
        (void*)&e_Wih0, (void*)&e_Whh0, (void*)&e_bih0, (void*)&e_bhh0,
        (void*)&e_Wih1, (void*)&e_Whh1, (void*)&e_bih1, (void*)&e_bhh1,
        (void*)&d_Whh0, (void*)&d_bih0, (void*)&d_bhh0,
        (void*)&d_Wih1, (void*)&d_Whh1, (void*)&d_bih1, (void*)&d_bhh1,
        (void*)&Mm, (void*)&bM,
        (void*)&fc_W, (void*)&fc_b,
        (void*)&h1a, (void*)&h1b, (void*)&h2a, (void*)&h2b,
        (void*)&bar,
        (void*)&out
    };
    hipLaunchCooperativeKernel((const void*)lstm_ae_persistent,
                               dim3(NWG), dim3(256), args, 0, stream);
}